// Round 15
// baseline (97.253 us; speedup 1.0000x reference)
//
#include <hip/hip_runtime.h>

#define CC 64
#define TT 8192
#define NB 8
#define NW32 16384          // 32-t windows: 64 b * 256
#define GRID 768            // 3 blocks/CU (3 waves/SIMD)
#define NWAVES (GRID * 4)   // 3072 waves; ~5.3 windows each

typedef __attribute__((ext_vector_type(8))) short bf16x8;
typedef __attribute__((ext_vector_type(16))) float f32x16;
typedef __attribute__((ext_vector_type(4))) int i32x4;

union I4B8 { i32x4 i; bf16x8 b; };

__device__ __forceinline__ unsigned short f32_to_bf16_rn(float f) {
    unsigned u = __float_as_uint(f);
    unsigned r = (u + 0x7FFFu + ((u >> 16) & 1u)) >> 16;
    return (unsigned short)r;
}
__device__ __forceinline__ float bf16_to_f32(unsigned short h) {
    return __uint_as_float(((unsigned)h) << 16);
}

// ---- main: persistent; W hi/lo 32x32-MFMA fragments in LDS (16 KB);
//      wave = 32-t window, all 64 rows via 2 M-tiles; zero steady barriers;
//      two-pass amax epilogue (no z register buffer -> no spill). -----------
__global__ __launch_bounds__(256, 3) void rpg_main(
    const float* __restrict__ x,
    const float* __restrict__ sigma,
    const float* __restrict__ rho,
    const float* __restrict__ E,
    const float* __restrict__ F,
    float* __restrict__ out)
{
    __shared__ __align__(16) char wsl[16384];

    const int tid  = threadIdx.x;
    const int w    = tid >> 6;
    const int lane = tid & 63;
    const int l31  = lane & 31;      // t within window; MFMA A-row/B-col/D-col
    const int hi   = lane >> 5;      // k-group (A/B); row-half selector (D)

    // ---- build W fragments in LDS, once per block (verified R14) ------------
    {
        const int r = tid >> 6;
        const int c = tid & 63;
        const float g = (8.0f / (1e-5f + fabsf(sigma[r]))) *
                        (8.0f / (1e-5f + fabsf(rho[r]))) * 0.25f;
        const int ks = c >> 4, h5 = (c >> 3) & 1, j = c & 7;
        const float4 e0 = *(const float4*)(E + (r * 64 + c) * 8);
        const float4 e1 = *(const float4*)(E + (r * 64 + c) * 8 + 4);
        const float4 fq0 = *(const float4*)(F + (r * 64 + c) * 8);
        const float4 fq1 = *(const float4*)(F + (r * 64 + c) * 8 + 4);
        const float ev[8] = {e0.x, e0.y, e0.z, e0.w, e1.x, e1.y, e1.z, e1.w};
        const float fv[8] = {fq0.x, fq0.y, fq0.z, fq0.w, fq1.x, fq1.y, fq1.z, fq1.w};
        #pragma unroll
        for (int n = 0; n < 8; ++n) {
            const int pb = r * 8 + n;            // 0..31
            {   // E side: mt = 0, scaled
                const float val = ev[n] * g;
                const unsigned short hv = f32_to_bf16_rn(val);
                const unsigned short lv = f32_to_bf16_rn(val - bf16_to_f32(hv));
                char* base = wsl + ((((0 * 4 + ks) * 2 + 0) * 64 + (h5 << 5) + pb) << 4) + j * 2;
                *(unsigned short*)base = hv;
                *(unsigned short*)(base + 1024) = lv;
            }
            {   // F side: mt = 1, unscaled
                const float val = fv[n];
                const unsigned short hv = f32_to_bf16_rn(val);
                const unsigned short lv = f32_to_bf16_rn(val - bf16_to_f32(hv));
                char* base = wsl + ((((1 * 4 + ks) * 2 + 0) * 64 + (h5 << 5) + pb) << 4) + j * 2;
                *(unsigned short*)base = hv;
                *(unsigned short*)(base + 1024) = lv;
            }
        }
    }

    int wid = blockIdx.x * 4 + w;

    // ---- prefetch window 0: B-frag order, full 128-B line segments ----------
    float f[32];
    {
        const int b = wid >> 8, t0 = (wid & 255) << 5;
        const float* xp = x + b * (CC * TT) + t0 + l31;
        #pragma unroll
        for (int k = 0; k < 32; ++k) {
            const int c = (k >> 3) * 16 + hi * 8 + (k & 7);
            f[k] = xp[c * TT];
        }
    }

    __syncthreads();   // W build complete (the only barrier)

    #pragma unroll 1
    while (wid < NW32) {
        // ---- convert f -> bf16 hi/lo B-frags (f dies here) ------------------
        bf16x8 xh[4], xl[4];
        #pragma unroll
        for (int ks = 0; ks < 4; ++ks) {
            unsigned hw[4], lw[4];
            #pragma unroll
            for (int k = 0; k < 4; ++k) {
                const float f0 = f[ks * 8 + 2 * k];
                const float f1 = f[ks * 8 + 2 * k + 1];
                const unsigned u0 = __float_as_uint(f0), u1 = __float_as_uint(f1);
                hw[k] = (u0 >> 16) | (u1 & 0xFFFF0000u);
                const float h0 = __uint_as_float(u0 & 0xFFFF0000u);
                const float h1 = __uint_as_float(u1 & 0xFFFF0000u);
                lw[k] = (__float_as_uint(f0 - h0) >> 16) |
                        (__float_as_uint(f1 - h1) & 0xFFFF0000u);
            }
            I4B8 H, L;
            H.i = (i32x4){(int)hw[0], (int)hw[1], (int)hw[2], (int)hw[3]};
            L.i = (i32x4){(int)lw[0], (int)lw[1], (int)lw[2], (int)lw[3]};
            xh[ks] = H.b;
            xl[ks] = L.b;
        }

        const int b  = wid >> 8;
        const int t0 = (wid & 255) << 5;
        const int nxt = wid + NWAVES;

        // ---- prefetch next window (flies under MFMA + epilogue + stores) ----
        if (nxt < NW32) {
            const int nb = nxt >> 8, nt0 = (nxt & 255) << 5;
            const float* xp = x + nb * (CC * TT) + nt0 + l31;
            #pragma unroll
            for (int k = 0; k < 32; ++k) {
                const int c = (k >> 3) * 16 + hi * 8 + (k & 7);
                f[k] = xp[c * TT];
            }
        }

        // ---- GEMM: 3-pass hi/lo, 32x32x16 ----------------------------------
        f32x16 acc0 = {}, acc1 = {};
        #pragma unroll
        for (int ks = 0; ks < 4; ++ks) {
            const int fb0 = ((0 * 4 + ks) * 2) * 1024 + lane * 16;
            const bf16x8 wh0 = ((const I4B8*)(wsl + fb0))->b;
            const bf16x8 wl0 = ((const I4B8*)(wsl + fb0 + 1024))->b;
            acc0 = __builtin_amdgcn_mfma_f32_32x32x16_bf16(wh0, xh[ks], acc0, 0, 0, 0);
            acc0 = __builtin_amdgcn_mfma_f32_32x32x16_bf16(wh0, xl[ks], acc0, 0, 0, 0);
            acc0 = __builtin_amdgcn_mfma_f32_32x32x16_bf16(wl0, xh[ks], acc0, 0, 0, 0);
        }
        #pragma unroll
        for (int ks = 0; ks < 4; ++ks) {
            const int fb1 = ((1 * 4 + ks) * 2) * 1024 + lane * 16;
            const bf16x8 wh1 = ((const I4B8*)(wsl + fb1))->b;
            const bf16x8 wl1 = ((const I4B8*)(wsl + fb1 + 1024))->b;
            acc1 = __builtin_amdgcn_mfma_f32_32x32x16_bf16(wh1, xh[ks], acc1, 0, 0, 0);
            acc1 = __builtin_amdgcn_mfma_f32_32x32x16_bf16(wh1, xl[ks], acc1, 0, 0, 0);
            acc1 = __builtin_amdgcn_mfma_f32_32x32x16_bf16(wl1, xh[ks], acc1, 0, 0, 0);
        }

        // ---- epilogue, two-pass (no z buffer) -------------------------------
        // acc0 reg rank*4+ni -> xe[rank][n=ni+4hi]; acc1 -> xf[rank][m=mi+4hi];
        // partner(l^32) acc1 = other m-half.
        float xfo[16];
        #pragma unroll
        for (int i = 0; i < 16; ++i) xfo[i] = __shfl_xor(acc1[i], 32);

        // pass 1: amax = max |a|  (|z| is monotone in |a|)
        float amax = 0.0f;
        #pragma unroll
        for (int ni = 0; ni < 4; ++ni) {
            #pragma unroll
            for (int mi = 0; mi < 4; ++mi) {
                float a = acc0[0 + ni] * acc1[0 + mi];
                a = fmaf(acc0[4 + ni],  acc1[4 + mi],  a);
                a = fmaf(acc0[8 + ni],  acc1[8 + mi],  a);
                a = fmaf(acc0[12 + ni], acc1[12 + mi], a);
                amax = fmaxf(amax, fabsf(a));
                float a2 = acc0[0 + ni] * xfo[0 + mi];
                a2 = fmaf(acc0[4 + ni],  xfo[4 + mi],  a2);
                a2 = fmaf(acc0[8 + ni],  xfo[8 + mi],  a2);
                a2 = fmaf(acc0[12 + ni], xfo[12 + mi], a2);
                amax = fmaxf(amax, fabsf(a2));
            }
        }
        amax = fmaxf(amax, __shfl_xor(amax, 32));
        const float pm   = __builtin_amdgcn_sqrtf(amax + 0.01f) - 0.1f;
        const float rinv = __builtin_amdgcn_rcpf(pm + 1e-5f);

        // pass 2: recompute a, signed-sqrt, scale, store immediately
        float* ob  = out + b * (64 * TT) + t0 + l31;
        float* ob1 = ob + (36 * hi) * TT;            // own m-half rows
        float* ob2 = ob + (28 * hi + 4) * TT;        // partner m-half rows
        #pragma unroll
        for (int ni = 0; ni < 4; ++ni) {
            #pragma unroll
            for (int mi = 0; mi < 4; ++mi) {
                float a = acc0[0 + ni] * acc1[0 + mi];
                a = fmaf(acc0[4 + ni],  acc1[4 + mi],  a);
                a = fmaf(acc0[8 + ni],  acc1[8 + mi],  a);
                a = fmaf(acc0[12 + ni], acc1[12 + mi], a);
                float s = __builtin_amdgcn_sqrtf(fabsf(a) + 0.01f) - 0.1f;
                ob1[(ni * 8 + mi) * TT] = copysignf(s, a) * rinv;

                float a2 = acc0[0 + ni] * xfo[0 + mi];
                a2 = fmaf(acc0[4 + ni],  xfo[4 + mi],  a2);
                a2 = fmaf(acc0[8 + ni],  xfo[8 + mi],  a2);
                a2 = fmaf(acc0[12 + ni], xfo[12 + mi], a2);
                float s2 = __builtin_amdgcn_sqrtf(fabsf(a2) + 0.01f) - 0.1f;
                ob2[(ni * 8 + mi) * TT] = copysignf(s2, a2) * rinv;
            }
        }

        wid = nxt;
    }
}

extern "C" void kernel_launch(void* const* d_in, const int* in_sizes, int n_in,
                              void* d_out, int out_size, void* d_ws, size_t ws_size,
                              hipStream_t stream) {
    const float* x     = (const float*)d_in[0];
    const float* sigma = (const float*)d_in[1];
    const float* rho   = (const float*)d_in[2];
    const float* E     = (const float*)d_in[3];
    const float* F     = (const float*)d_in[4];
    float* out = (float*)d_out;

    rpg_main<<<GRID, 256, 0, stream>>>(x, sigma, rho, E, F, out);
}

// Round 16
// 65.264 us; speedup vs baseline: 1.4901x; 1.4901x over previous
//
#include <hip/hip_runtime.h>

#define CC 64
#define TT 8192
#define NB 8
#define NW32 16384          // 32-t windows: 64 b * 256
#define GRID 1024           // 4 blocks/CU x 4 waves = 16 waves/CU
#define NWAVES (GRID * 4)   // 4096 waves; exactly 4 windows each

typedef __attribute__((ext_vector_type(8))) short bf16x8;
typedef __attribute__((ext_vector_type(16))) float f32x16;
typedef __attribute__((ext_vector_type(4))) int i32x4;

union I4B8 { i32x4 i; bf16x8 b; };

__device__ __forceinline__ unsigned short f32_to_bf16_rn(float f) {
    unsigned u = __float_as_uint(f);
    unsigned r = (u + 0x7FFFu + ((u >> 16) & 1u)) >> 16;
    return (unsigned short)r;
}
__device__ __forceinline__ float bf16_to_f32(unsigned short h) {
    return __uint_as_float(((unsigned)h) << 16);
}

// ---- main: persistent; W hi/lo 32x32-MFMA fragments in LDS (16 KB);
//      wave = 32-t window, all 64 rows via 2 M-tiles; zero steady barriers;
//      NO register prefetch (TLP hides latency; avoids the f[32] spill). ----
__global__ __launch_bounds__(256, 4) void rpg_main(
    const float* __restrict__ x,
    const float* __restrict__ sigma,
    const float* __restrict__ rho,
    const float* __restrict__ E,
    const float* __restrict__ F,
    float* __restrict__ out)
{
    __shared__ __align__(16) char wsl[16384];

    const int tid  = threadIdx.x;
    const int w    = tid >> 6;
    const int lane = tid & 63;
    const int l31  = lane & 31;      // t within window; MFMA A-row/B-col/D-col
    const int hi   = lane >> 5;      // k-group (A/B); row-half selector (D)

    // ---- build W fragments in LDS, once per block (verified R14) ------------
    {
        const int r = tid >> 6;
        const int c = tid & 63;
        const float g = (8.0f / (1e-5f + fabsf(sigma[r]))) *
                        (8.0f / (1e-5f + fabsf(rho[r]))) * 0.25f;
        const int ks = c >> 4, h5 = (c >> 3) & 1, j = c & 7;
        const float4 e0 = *(const float4*)(E + (r * 64 + c) * 8);
        const float4 e1 = *(const float4*)(E + (r * 64 + c) * 8 + 4);
        const float4 fq0 = *(const float4*)(F + (r * 64 + c) * 8);
        const float4 fq1 = *(const float4*)(F + (r * 64 + c) * 8 + 4);
        const float ev[8] = {e0.x, e0.y, e0.z, e0.w, e1.x, e1.y, e1.z, e1.w};
        const float fv[8] = {fq0.x, fq0.y, fq0.z, fq0.w, fq1.x, fq1.y, fq1.z, fq1.w};
        #pragma unroll
        for (int n = 0; n < 8; ++n) {
            const int pb = r * 8 + n;            // 0..31
            {   // E side: mt = 0, scaled
                const float val = ev[n] * g;
                const unsigned short hv = f32_to_bf16_rn(val);
                const unsigned short lv = f32_to_bf16_rn(val - bf16_to_f32(hv));
                char* base = wsl + ((((0 * 4 + ks) * 2 + 0) * 64 + (h5 << 5) + pb) << 4) + j * 2;
                *(unsigned short*)base = hv;
                *(unsigned short*)(base + 1024) = lv;
            }
            {   // F side: mt = 1, unscaled
                const float val = fv[n];
                const unsigned short hv = f32_to_bf16_rn(val);
                const unsigned short lv = f32_to_bf16_rn(val - bf16_to_f32(hv));
                char* base = wsl + ((((1 * 4 + ks) * 2 + 0) * 64 + (h5 << 5) + pb) << 4) + j * 2;
                *(unsigned short*)base = hv;
                *(unsigned short*)(base + 1024) = lv;
            }
        }
    }

    __syncthreads();   // W build complete (the only barrier)

    int wid = blockIdx.x * 4 + w;

    #pragma unroll 1
    while (wid < NW32) {
        const int b  = wid >> 8;
        const int t0 = (wid & 255) << 5;

        // ---- load x (full 128-B line segments) + convert to bf16 hi/lo ------
        // f[] has a SHORT live range: dies at end of this scope (no spill).
        bf16x8 xh[4], xl[4];
        {
            const float* xp = x + b * (CC * TT) + t0 + l31;
            float f[32];
            #pragma unroll
            for (int k = 0; k < 32; ++k) {
                const int c = (k >> 3) * 16 + hi * 8 + (k & 7);
                f[k] = xp[c * TT];
            }
            #pragma unroll
            for (int ks = 0; ks < 4; ++ks) {
                unsigned hw[4], lw[4];
                #pragma unroll
                for (int k = 0; k < 4; ++k) {
                    const float f0 = f[ks * 8 + 2 * k];
                    const float f1 = f[ks * 8 + 2 * k + 1];
                    const unsigned u0 = __float_as_uint(f0), u1 = __float_as_uint(f1);
                    hw[k] = (u0 >> 16) | (u1 & 0xFFFF0000u);
                    const float h0 = __uint_as_float(u0 & 0xFFFF0000u);
                    const float h1 = __uint_as_float(u1 & 0xFFFF0000u);
                    lw[k] = (__float_as_uint(f0 - h0) >> 16) |
                            (__float_as_uint(f1 - h1) & 0xFFFF0000u);
                }
                I4B8 H, L;
                H.i = (i32x4){(int)hw[0], (int)hw[1], (int)hw[2], (int)hw[3]};
                L.i = (i32x4){(int)lw[0], (int)lw[1], (int)lw[2], (int)lw[3]};
                xh[ks] = H.b;
                xl[ks] = L.b;
            }
        }

        // ---- GEMM: 3-pass hi/lo, 32x32x16 ----------------------------------
        f32x16 acc0 = {}, acc1 = {};
        #pragma unroll
        for (int ks = 0; ks < 4; ++ks) {
            const int fb0 = ((0 * 4 + ks) * 2) * 1024 + lane * 16;
            const bf16x8 wh0 = ((const I4B8*)(wsl + fb0))->b;
            const bf16x8 wl0 = ((const I4B8*)(wsl + fb0 + 1024))->b;
            acc0 = __builtin_amdgcn_mfma_f32_32x32x16_bf16(wh0, xh[ks], acc0, 0, 0, 0);
            acc0 = __builtin_amdgcn_mfma_f32_32x32x16_bf16(wh0, xl[ks], acc0, 0, 0, 0);
            acc0 = __builtin_amdgcn_mfma_f32_32x32x16_bf16(wl0, xh[ks], acc0, 0, 0, 0);
        }
        #pragma unroll
        for (int ks = 0; ks < 4; ++ks) {
            const int fb1 = ((1 * 4 + ks) * 2) * 1024 + lane * 16;
            const bf16x8 wh1 = ((const I4B8*)(wsl + fb1))->b;
            const bf16x8 wl1 = ((const I4B8*)(wsl + fb1 + 1024))->b;
            acc1 = __builtin_amdgcn_mfma_f32_32x32x16_bf16(wh1, xh[ks], acc1, 0, 0, 0);
            acc1 = __builtin_amdgcn_mfma_f32_32x32x16_bf16(wh1, xl[ks], acc1, 0, 0, 0);
            acc1 = __builtin_amdgcn_mfma_f32_32x32x16_bf16(wl1, xh[ks], acc1, 0, 0, 0);
        }

        // ---- epilogue: own half kept in zo[16]; partner half recomputed -----
        // acc0 reg rank*4+ni -> xe[rank][n=ni+4hi]; acc1 -> xf[rank][m=mi+4hi];
        // partner(l^32) acc1 = other m-half.
        float xfo[16];
        #pragma unroll
        for (int i = 0; i < 16; ++i) xfo[i] = __shfl_xor(acc1[i], 32);

        float zo[16];              // own-half signed-sqrt values
        float amax = 0.0f;
        #pragma unroll
        for (int ni = 0; ni < 4; ++ni) {
            #pragma unroll
            for (int mi = 0; mi < 4; ++mi) {
                float a = acc0[0 + ni] * acc1[0 + mi];
                a = fmaf(acc0[4 + ni],  acc1[4 + mi],  a);
                a = fmaf(acc0[8 + ni],  acc1[8 + mi],  a);
                a = fmaf(acc0[12 + ni], acc1[12 + mi], a);
                amax = fmaxf(amax, fabsf(a));
                float s = __builtin_amdgcn_sqrtf(fabsf(a) + 0.01f) - 0.1f;
                zo[ni * 4 + mi] = copysignf(s, a);

                float a2 = acc0[0 + ni] * xfo[0 + mi];
                a2 = fmaf(acc0[4 + ni],  xfo[4 + mi],  a2);
                a2 = fmaf(acc0[8 + ni],  xfo[8 + mi],  a2);
                a2 = fmaf(acc0[12 + ni], xfo[12 + mi], a2);
                amax = fmaxf(amax, fabsf(a2));
            }
        }
        amax = fmaxf(amax, __shfl_xor(amax, 32));
        const float pm   = __builtin_amdgcn_sqrtf(amax + 0.01f) - 0.1f;
        const float rinv = __builtin_amdgcn_rcpf(pm + 1e-5f);

        float* ob  = out + b * (64 * TT) + t0 + l31;
        float* ob1 = ob + (36 * hi) * TT;            // own m-half rows
        float* ob2 = ob + (28 * hi + 4) * TT;        // partner m-half rows
        #pragma unroll
        for (int ni = 0; ni < 4; ++ni) {
            #pragma unroll
            for (int mi = 0; mi < 4; ++mi) {
                ob1[(ni * 8 + mi) * TT] = zo[ni * 4 + mi] * rinv;

                float a2 = acc0[0 + ni] * xfo[0 + mi];
                a2 = fmaf(acc0[4 + ni],  xfo[4 + mi],  a2);
                a2 = fmaf(acc0[8 + ni],  xfo[8 + mi],  a2);
                a2 = fmaf(acc0[12 + ni], xfo[12 + mi], a2);
                float s2 = __builtin_amdgcn_sqrtf(fabsf(a2) + 0.01f) - 0.1f;
                ob2[(ni * 8 + mi) * TT] = copysignf(s2, a2) * rinv;
            }
        }

        wid += NWAVES;
    }
}

extern "C" void kernel_launch(void* const* d_in, const int* in_sizes, int n_in,
                              void* d_out, int out_size, void* d_ws, size_t ws_size,
                              hipStream_t stream) {
    const float* x     = (const float*)d_in[0];
    const float* sigma = (const float*)d_in[1];
    const float* rho   = (const float*)d_in[2];
    const float* E     = (const float*)d_in[3];
    const float* F     = (const float*)d_in[4];
    float* out = (float*)d_out;

    rpg_main<<<GRID, 256, 0, stream>>>(x, sigma, rho, E, F, out);
}

// Round 17
// 50.421 us; speedup vs baseline: 1.9288x; 1.2944x over previous
//
#include <hip/hip_runtime.h>

#define CC 64
#define TT 8192
#define NB 8
#define NWIN 8192          // 64 b * 128 windows of 64 t
#define GRID 768           // 3 blocks/CU * 256 CUs

typedef __attribute__((ext_vector_type(8))) short bf16x8;
typedef __attribute__((ext_vector_type(4))) float f32x4;
typedef __attribute__((ext_vector_type(4))) int i32x4;

union I4B8 { i32x4 i; bf16x8 b; };

__device__ __forceinline__ unsigned short f32_to_bf16_rn(float f) {
    unsigned u = __float_as_uint(f);
    unsigned r = (u + 0x7FFFu + ((u >> 16) & 1u)) >> 16;
    return (unsigned short)r;
}
__device__ __forceinline__ float bf16_to_f32(unsigned short h) {
    return __uint_as_float(((unsigned)h) << 16);
}

// LDS: [0,16K) W frags; [16K,32K) xbuf0 (xh 8K + xl 8K); [32K,48K) xbuf1
__global__ __launch_bounds__(256, 3) void rpg_fused(
    const float* __restrict__ x,
    const float* __restrict__ sigma,
    const float* __restrict__ rho,
    const float* __restrict__ E,
    const float* __restrict__ F,
    float* __restrict__ out)
{
    __shared__ __align__(16) char smem[49152];
    char* wsl = smem;

    const int tid  = threadIdx.x;
    const int w    = tid >> 6;
    const int lane = tid & 63;
    const int am   = lane & 15;
    const int ag   = lane >> 4;

    // ---- build W fragments in LDS, once per block (verified R10 builder) ----
    {
        const int r = tid >> 6;
        const int c = tid & 63;
        const float g = (8.0f / (1e-5f + fabsf(sigma[r]))) *
                        (8.0f / (1e-5f + fabsf(rho[r]))) * 0.25f;
        const int wks = c >> 5, wag = (c >> 3) & 3, wj = c & 7;
        const float4 e0 = *(const float4*)(E + (r * 64 + c) * 8);
        const float4 e1 = *(const float4*)(E + (r * 64 + c) * 8 + 4);
        const float4 fv0 = *(const float4*)(F + (r * 64 + c) * 8);
        const float4 fv1 = *(const float4*)(F + (r * 64 + c) * 8 + 4);
        const float ev[8] = {e0.x, e0.y, e0.z, e0.w, e1.x, e1.y, e1.z, e1.w};
        const float fv[8] = {fv0.x, fv0.y, fv0.z, fv0.w, fv1.x, fv1.y, fv1.z, fv1.w};
        #pragma unroll
        for (int n = 0; n < 8; ++n) {
            {   // E side: p = r*8+n (scaled)
                const int p = r * 8 + n;
                const float val = ev[n] * g;
                const unsigned short hi = f32_to_bf16_rn(val);
                const unsigned short lo = f32_to_bf16_rn(val - bf16_to_f32(hi));
                const int mt = p >> 4, pam = p & 15;
                char* base = wsl + ((((mt * 2 + wks) * 2 + 0) * 64 + wag * 16 + pam) << 4) + wj * 2;
                *(unsigned short*)base = hi;
                *(unsigned short*)(base + 1024) = lo;
            }
            {   // F side: p = 32 + r*8+n (unscaled)
                const int p = 32 + r * 8 + n;
                const float val = fv[n];
                const unsigned short hi = f32_to_bf16_rn(val);
                const unsigned short lo = f32_to_bf16_rn(val - bf16_to_f32(hi));
                const int mt = p >> 4, pam = p & 15;
                char* base = wsl + ((((mt * 2 + wks) * 2 + 0) * 64 + wag * 16 + pam) << 4) + wj * 2;
                *(unsigned short*)base = hi;
                *(unsigned short*)(base + 1024) = lo;
            }
        }
    }

    // ---- chunked, contiguous window range per block (DRAM page locality) ----
    // first 512 blocks: 11 windows; rest: 10.  Block's region is contiguous
    // in (b, t): writes per output row become sequential 256-B bursts.
    const int extra = NWIN - GRID * 10;            // 512
    int wid, wend;
    if ((int)blockIdx.x < extra) { wid = blockIdx.x * 11;                      wend = wid + 11; }
    else                         { wid = extra * 11 + (blockIdx.x - extra) * 10; wend = wid + 10; }

    // ---- prefetch window 0 --------------------------------------------------
    float f[16];
    {
        const int b = wid >> 7, t0 = (wid & 127) << 6;
        const float* xcol = x + b * (CC * TT) + t0 + lane;
        #pragma unroll
        for (int k = 0; k < 16; ++k) f[k] = xcol[(w * 16 + k) * TT];
    }

    int ibuf = 0;
    const bool ra0 = (ag & 2) == 0;
    const bool qlo = (ag & 1) == 0;

    #pragma unroll 1
    while (wid < wend) {
        char* xbuf = ibuf ? (smem + 32768) : (smem + 16384);

        // ---- convert f -> bf16 hi/lo, ds_write with XOR swizzle -------------
        {
            unsigned hw[8], lw[8];
            #pragma unroll
            for (int k = 0; k < 8; ++k) {
                const unsigned u0 = __float_as_uint(f[2 * k]);
                const unsigned u1 = __float_as_uint(f[2 * k + 1]);
                hw[k] = (u0 >> 16) | (u1 & 0xFFFF0000u);
                const float h0 = __uint_as_float(u0 & 0xFFFF0000u);
                const float h1 = __uint_as_float(u1 & 0xFFFF0000u);
                lw[k] = (__float_as_uint(f[2 * k] - h0) >> 16) |
                        (__float_as_uint(f[2 * k + 1] - h1) & 0xFFFF0000u);
            }
            const int sw = lane & 7;
            char* hb = xbuf + lane * 128;
            char* lb = xbuf + 8192 + lane * 128;
            *(i32x4*)(hb + (((2 * w    ) ^ sw) * 16)) = (i32x4){(int)hw[0], (int)hw[1], (int)hw[2], (int)hw[3]};
            *(i32x4*)(hb + (((2 * w + 1) ^ sw) * 16)) = (i32x4){(int)hw[4], (int)hw[5], (int)hw[6], (int)hw[7]};
            *(i32x4*)(lb + (((2 * w    ) ^ sw) * 16)) = (i32x4){(int)lw[0], (int)lw[1], (int)lw[2], (int)lw[3]};
            *(i32x4*)(lb + (((2 * w + 1) ^ sw) * 16)) = (i32x4){(int)lw[4], (int)lw[5], (int)lw[6], (int)lw[7]};
        }

        const int b  = wid >> 7;
        const int t0 = (wid & 127) << 6;
        const int next = wid + 1;

        __syncthreads();

        // ---- B-frags from LDS (reused across the 4 M-tiles) -----------------
        bf16x8 xh[2], xl[2];
        {
            const int trow = w * 16 + am;
            const int sw   = trow & 7;
            #pragma unroll
            for (int ks = 0; ks < 2; ++ks) {
                const int g2  = (ks * 4 + ag) ^ sw;
                const int off = trow * 128 + g2 * 16;
                xh[ks] = ((const I4B8*)(xbuf + off))->b;
                xl[ks] = ((const I4B8*)(xbuf + 8192 + off))->b;
            }
        }

        // ---- prefetch next window (after barrier: flies under compute) ------
        if (next < wend) {
            const int nbx = next >> 7, nt0 = (next & 127) << 6;
            const float* xcol = x + nbx * (CC * TT) + nt0 + lane;
            #pragma unroll
            for (int k = 0; k < 16; ++k) f[k] = xcol[(w * 16 + k) * TT];
        }

        // ---- GEMM: acc[mt][r] = Y[p = mt*16 + ag*4 + r][t0 + w*16 + am] -----
        f32x4 acc[4];
        #pragma unroll
        for (int mt = 0; mt < 4; ++mt) {
            acc[mt] = (f32x4){0.0f, 0.0f, 0.0f, 0.0f};
            #pragma unroll
            for (int ks = 0; ks < 2; ++ks) {
                const int fb = ((mt * 2 + ks) * 2) * 1024 + lane * 16;
                const bf16x8 wh = ((const I4B8*)(wsl + fb))->b;
                const bf16x8 wl = ((const I4B8*)(wsl + fb + 1024))->b;
                acc[mt] = __builtin_amdgcn_mfma_f32_16x16x32_bf16(wh, xh[ks], acc[mt], 0, 0, 0);
                acc[mt] = __builtin_amdgcn_mfma_f32_16x16x32_bf16(wh, xl[ks], acc[mt], 0, 0, 0);
                acc[mt] = __builtin_amdgcn_mfma_f32_16x16x32_bf16(wl, xh[ks], acc[mt], 0, 0, 0);
            }
        }

        // ---- in-register epilogue (verified lane algebra) -------------------
        float pA[4], pB[4], pC[4], pD[4];
        #pragma unroll
        for (int i = 0; i < 4; ++i) {
            pA[i] = __shfl_xor(acc[0][i], 32);
            pB[i] = __shfl_xor(acc[1][i], 32);
            pC[i] = __shfl_xor(acc[2][i], 32);
            pD[i] = __shfl_xor(acc[3][i], 32);
        }

        float xe_[4][2];
        #pragma unroll
        for (int e = 0; e < 2; ++e) {
            xe_[0][e] = ra0 ? acc[0][e] : pA[2 + e];
            xe_[1][e] = ra0 ? pA[e]     : acc[0][2 + e];
            xe_[2][e] = ra0 ? acc[1][e] : pB[2 + e];
            xe_[3][e] = ra0 ? pB[e]     : acc[1][2 + e];
        }

        float xfq0[4], xfq1[4], xfq2[4], xfq3[4];
        #pragma unroll
        for (int i = 0; i < 4; ++i) {
            xfq0[i] = ra0 ? acc[2][i] : pC[i];
            xfq1[i] = ra0 ? pC[i]     : acc[2][i];
            xfq2[i] = ra0 ? acc[3][i] : pD[i];
            xfq3[i] = ra0 ? pD[i]     : acc[3][i];
        }
        float xfo0[4], xfo1[4], xfo2[4], xfo3[4];
        #pragma unroll
        for (int i = 0; i < 4; ++i) {
            xfo0[i] = __shfl_xor(xfq0[i], 16);
            xfo1[i] = __shfl_xor(xfq1[i], 16);
            xfo2[i] = __shfl_xor(xfq2[i], 16);
            xfo3[i] = __shfl_xor(xfq3[i], 16);
        }
        float xfL[4][4], xfH[4][4];
        #pragma unroll
        for (int i = 0; i < 4; ++i) {
            xfL[0][i] = qlo ? xfq0[i] : xfo0[i];  xfH[0][i] = qlo ? xfo0[i] : xfq0[i];
            xfL[1][i] = qlo ? xfq1[i] : xfo1[i];  xfH[1][i] = qlo ? xfo1[i] : xfq1[i];
            xfL[2][i] = qlo ? xfq2[i] : xfo2[i];  xfH[2][i] = qlo ? xfo2[i] : xfq2[i];
            xfL[3][i] = qlo ? xfq3[i] : xfo3[i];  xfH[3][i] = qlo ? xfo3[i] : xfq3[i];
        }

        float z[2][8];
        float pm = 0.0f;
        #pragma unroll
        for (int e = 0; e < 2; ++e) {
            #pragma unroll
            for (int m = 0; m < 4; ++m) {
                float a = xe_[0][e] * xfL[0][m];
                a = fmaf(xe_[1][e], xfL[1][m], a);
                a = fmaf(xe_[2][e], xfL[2][m], a);
                a = fmaf(xe_[3][e], xfL[3][m], a);
                float s = __builtin_amdgcn_sqrtf(fabsf(a) + 0.01f) - 0.1f;
                float v = copysignf(s, a);
                z[e][m] = v;
                pm = fmaxf(pm, fabsf(v));
            }
            #pragma unroll
            for (int m = 0; m < 4; ++m) {
                float a = xe_[0][e] * xfH[0][m];
                a = fmaf(xe_[1][e], xfH[1][m], a);
                a = fmaf(xe_[2][e], xfH[2][m], a);
                a = fmaf(xe_[3][e], xfH[3][m], a);
                float s = __builtin_amdgcn_sqrtf(fabsf(a) + 0.01f) - 0.1f;
                float v = copysignf(s, a);
                z[e][4 + m] = v;
                pm = fmaxf(pm, fabsf(v));
            }
        }

        pm = fmaxf(pm, __shfl_xor(pm, 16));
        pm = fmaxf(pm, __shfl_xor(pm, 32));
        const float rinv = __builtin_amdgcn_rcpf(pm + 1e-5f);

        const int nbase = (qlo ? 0 : 4) + (ra0 ? 0 : 2);
        float* ob = out + b * (64 * TT) + t0 + w * 16 + am;
        #pragma unroll
        for (int e = 0; e < 2; ++e)
            #pragma unroll
            for (int m = 0; m < 8; ++m)
                ob[((nbase + e) * NB + m) * TT] = z[e][m] * rinv;

        wid = next;
        ibuf ^= 1;
    }
}

extern "C" void kernel_launch(void* const* d_in, const int* in_sizes, int n_in,
                              void* d_out, int out_size, void* d_ws, size_t ws_size,
                              hipStream_t stream) {
    const float* x     = (const float*)d_in[0];
    const float* sigma = (const float*)d_in[1];
    const float* rho   = (const float*)d_in[2];
    const float* E     = (const float*)d_in[3];
    const float* F     = (const float*)d_in[4];
    float* out = (float*)d_out;

    rpg_fused<<<GRID, 256, 0, stream>>>(x, sigma, rho, E, F, out);
}